// Round 1
// baseline (137.926 us; speedup 1.0000x reference)
//
#include <hip/hip_runtime.h>

// Problem constants
#define BB 8
#define HH 640
#define WW 640
#define HWN (HH * WW)          // 409600 pixels per batch
#define NUM_INST 16
#define NBLK 128               // blocks per batch -> 1024 total = exactly 4 blocks/CU
#define NBLK_TOT (NBLK * BB)
#define THREADS 256
#define NV 36                  // 16 s12 | 16 cnt | pos, all, or, posCnt
#define NVEC (HWN / 4)         // 102400 float4 per batch
#define VPB (NVEC / NBLK)      // 800 float4 per block -> perfectly balanced blocks

// ws layout: ws[v * NBLK_TOT + g], g = b*NBLK + blockIdx.x. 36*1024*4 = 147456 B.
// Plain stores, no zero-init needed.

__device__ __forceinline__ void process_pixel(
    float p1, float p2, float c, float t, int k, int tid,
    float (&s_e)[NUM_INST][THREADS], float (&s_c)[NUM_INST][THREADS],
    float& lgPos, float& lgAll, float& lgOr, float& accCnt)
{
    float andp = p1 * p2;
    // BCE(and_preds, overlap): overlap exactly 0/1 -> one log, select the argument.
    // Clip at -100 never engages: inputs in [1e-4, 1-1e-4].
    // Accumulate log2; scale by ln2 and negate ONCE in the epilogue.
    float argA = (t != 0.0f) ? andp : (1.0f - andp);
    float lg = __log2f(argA);          // raw v_log_f32, no per-pixel *ln2
    lgAll += lg;
    lgPos = fmaf(c, lg, lgPos);        // c is exactly 0.0/1.0
    accCnt += c;
    // BCE(max(p1,p2), conf): conf exactly 0/1
    float mx = fmaxf(p1, p2);
    float argO = (c != 0.0f) ? mx : (1.0f - mx);
    lgOr += __log2f(argO);
    // instance term: |d1-d2| = |s1-s2|/cnt, accumulate e1-e2 only
    float ao = t * andp;               // t is exactly 0.0/1.0
    float d1 = fmaxf(p1, ao) - 1.0f;
    float d2 = fmaxf(p2, ao) - 1.0f;
    float e12 = (d1 - d2) * (d1 + d2);
    // Per-thread LDS bins: address word = k*256 + tid -> bank = tid%32 -> 2-way
    // aliasing (free, m136). Column `tid` is private to this thread; atomicAdd
    // is used only for its fire-and-forget ds_add_f32 form (no RMW dep chain,
    // no 16x cmp/cndmask/add VALU ladder).
    atomicAdd(&s_e[k][tid], e12);
    atomicAdd(&s_c[k][tid], 1.0f);
}

__global__ __launch_bounds__(THREADS) void overlap_main_kernel(
    const float* __restrict__ preds, const float* __restrict__ conf,
    const int* __restrict__ inst, const float* __restrict__ overlap,
    float* __restrict__ ws)
{
    __shared__ float s_e[NUM_INST][THREADS];   // 16 KiB  e12 sums
    __shared__ float s_c[NUM_INST][THREADS];   // 16 KiB  counts (exact ints in f32)
    __shared__ float wsum[4][NV];              // 576 B   -> 33.3 KiB total, 4 blocks/CU ok

    const int b   = blockIdx.y;
    const int tid = threadIdx.x;

    // Zero own columns only -> no barrier needed before the loop.
    #pragma unroll
    for (int j = 0; j < NUM_INST; ++j) { s_e[j][tid] = 0.0f; s_c[j][tid] = 0.0f; }

    const float4* p1v = (const float4*)(preds + (size_t)b * 2 * HWN);
    const float4* p2v = p1v + NVEC;
    const float4* cv  = (const float4*)(conf    + (size_t)b * HWN);
    const float4* tv  = (const float4*)(overlap + (size_t)b * HWN);
    const int4*   kv  = (const int4*)(inst      + (size_t)b * HWN);

    float lgPos = 0.0f, lgAll = 0.0f, lgOr = 0.0f, accCnt = 0.0f;

    // Contiguous 800-vec4 chunk per block: every block does identical work
    // (3 full iterations + one 32-thread partial), no cross-CU imbalance.
    const int lim = (blockIdx.x + 1) * VPB;
    for (int i = blockIdx.x * VPB + tid; i < lim; i += THREADS) {
        float4 A = p1v[i];
        float4 Bv = p2v[i];
        float4 C = cv[i];
        float4 T = tv[i];
        int4   K = kv[i];
        process_pixel(A.x, Bv.x, C.x, T.x, K.x, tid, s_e, s_c, lgPos, lgAll, lgOr, accCnt);
        process_pixel(A.y, Bv.y, C.y, T.y, K.y, tid, s_e, s_c, lgPos, lgAll, lgOr, accCnt);
        process_pixel(A.z, Bv.z, C.z, T.z, K.z, tid, s_e, s_c, lgPos, lgAll, lgOr, accCnt);
        process_pixel(A.w, Bv.w, C.w, T.w, K.w, tid, s_e, s_c, lgPos, lgAll, lgOr, accCnt);
    }

    // Gather own columns (in-order LDS pipe: prior ds_add_f32 complete before
    // ds_read of the same address; no cross-thread traffic on these columns).
    float fv[NV];
    #pragma unroll
    for (int j = 0; j < NUM_INST; ++j) { fv[j] = s_e[j][tid]; fv[16 + j] = s_c[j][tid]; }
    fv[32] = lgPos; fv[33] = lgAll; fv[34] = lgOr; fv[35] = accCnt;

    // Butterfly-reduce 36 per-lane floats across the wave
    #pragma unroll
    for (int s = 32; s > 0; s >>= 1) {
        #pragma unroll
        for (int v = 0; v < NV; ++v) fv[v] += __shfl_xor(fv[v], s, 64);
    }

    const int wave = tid >> 6;
    const int lane = tid & 63;
    if (lane == 0) {
        #pragma unroll
        for (int v = 0; v < NV; ++v) wsum[wave][v] = fv[v];
    }
    __syncthreads();
    if (tid < NV) {
        float s = wsum[0][tid] + wsum[1][tid] + wsum[2][tid] + wsum[3][tid];
        if (tid >= 32 && tid < 35)
            s = -0.69314718055994530942f * s;   // log2 -> -ln: posSum, allSum, orSum
        int g = blockIdx.y * NBLK + blockIdx.x;
        ws[tid * NBLK_TOT + g] = s;             // plain store, no atomics
    }
}

__global__ __launch_bounds__(320) void overlap_finalize_kernel(
    const float* __restrict__ ws, float* __restrict__ out)
{
    __shared__ float seg[BB][NV];
    __shared__ float perkey[BB][NUM_INST];
    __shared__ float pres[BB][NUM_INST];
    __shared__ float binst[BB];
    const int t = threadIdx.x;   // 320 >= 8*36 = 288

    if (t < BB * NV) {
        int b = t / NV, v = t - (t / NV) * NV;
        const float4* p = (const float4*)(ws + v * NBLK_TOT + b * NBLK);
        float4 s4 = {0.0f, 0.0f, 0.0f, 0.0f};
        #pragma unroll 8
        for (int i = 0; i < NBLK / 4; ++i) {   // 32 independent float4 loads
            float4 q = p[i];
            s4.x += q.x; s4.y += q.y; s4.z += q.z; s4.w += q.w;
        }
        seg[b][v] = (s4.x + s4.y) + (s4.z + s4.w);
    }
    __syncthreads();

    if (t < BB * NUM_INST) {
        int b = t >> 4, k = t & 15;
        float c = seg[b][16 + k];
        bool present = c > 0.0f;
        float sc = present ? c : 1.0f;
        perkey[b][k] = present ? (1.0f - fabsf(seg[b][k]) / sc) : 0.0f;
        pres[b][k]   = present ? 1.0f : 0.0f;
    }
    __syncthreads();

    if (t < BB) {
        float s = 0.0f, nk = 0.0f;
        for (int k = 0; k < NUM_INST; ++k) { s += perkey[t][k]; nk += pres[t][k]; }
        binst[t] = s / nk;
    }
    __syncthreads();

    if (t == 0) {
        float instLoss = 0.0f, posS = 0.0f, allS = 0.0f, orS = 0.0f, posC = 0.0f;
        for (int b = 0; b < BB; ++b) {
            instLoss += binst[b];
            posS += seg[b][32];
            allS += seg[b][33];
            orS  += seg[b][34];
            posC += seg[b][35];
        }
        instLoss *= (1.0f / (float)BB);
        const float N = (float)BB * (float)HWN;
        float negS = allS - posS;
        float andLoss = posS / posC + negS / (N - posC);
        float orLoss  = orS / N;
        out[0] = 0.5f * andLoss + 0.25f * orLoss + 0.25f * instLoss;
    }
}

extern "C" void kernel_launch(void* const* d_in, const int* in_sizes, int n_in,
                              void* d_out, int out_size, void* d_ws, size_t ws_size,
                              hipStream_t stream) {
    const float* preds   = (const float*)d_in[0];
    const float* conf    = (const float*)d_in[1];
    const int*   inst    = (const int*)d_in[2];
    const float* overlap = (const float*)d_in[3];
    // d_in[4] (inds) is unused by the reference computation.
    float* ws  = (float*)d_ws;
    float* out = (float*)d_out;

    dim3 grid(NBLK, BB);
    overlap_main_kernel<<<grid, THREADS, 0, stream>>>(preds, conf, inst, overlap, ws);
    overlap_finalize_kernel<<<1, 320, 0, stream>>>(ws, out);
}

// Round 2
// 117.208 us; speedup vs baseline: 1.1768x; 1.1768x over previous
//
#include <hip/hip_runtime.h>

// Problem constants
#define BB 8
#define HH 640
#define WW 640
#define HWN (HH * WW)          // 409600 pixels per batch
#define NUM_INST 16
#define NBLK 256               // blocks per batch -> 2048 total = 8 blocks/CU = 32 waves/CU
#define NBLK_TOT (NBLK * BB)
#define THREADS 256
#define NV 36                  // 16 s12 | 16 cnt | pos, all, or, posCnt
#define NVEC (HWN / 4)         // 102400 float4 per batch
#define VPB (NVEC / NBLK)      // 400 float4 per block -> perfectly balanced blocks

// ws layout: ws[v * NBLK_TOT + g], g = b*NBLK + blockIdx.x. 36*2048*4 = 294912 B.
// Plain stores, no zero-init needed.

__device__ __forceinline__ void process_pixel(
    float p1, float p2, float c, float t, int k,
    float* s12, unsigned* cnt_s,
    float& lgPos, float& lgAll, float& lgOr, float& accCnt)
{
    float andp = p1 * p2;
    bool tpos = (t != 0.0f);
    bool cpos = (c != 0.0f);
    // BCE(and_preds, overlap): overlap exactly 0/1 -> one log, select the argument.
    // Clip at -100 never engages: inputs in [1e-4, 1-1e-4].
    // Accumulate log2; scale by ln2 and negate ONCE in the epilogue.
    float argA = tpos ? andp : (1.0f - andp);
    float lg = __log2f(argA);          // raw v_log_f32
    lgAll += lg;
    lgPos = fmaf(c, lg, lgPos);        // c is exactly 0.0/1.0
    accCnt += c;
    // BCE(max(p1,p2), conf): conf exactly 0/1
    float mx = fmaxf(p1, p2);
    float argO = cpos ? mx : (1.0f - mx);
    lgOr += __log2f(argO);
    // instance term: |d1-d2| = |s1-s2|/cnt, accumulate e1-e2 only
    float ao = t * andp;               // t is exactly 0.0/1.0
    float d1 = fmaxf(p1, ao) - 1.0f;
    float d2 = fmaxf(p2, ao) - 1.0f;
    float e12 = (d1 - d2) * (d1 + d2);
    // Register binning ladder: ~48 VALU/pixel but only ~2 us total across the
    // chip (3.28M px / 64 lanes * 48 * 2cy / 1024 SIMDs). Counts ride the
    // scalar pipe via ballot+popcount. This beat LDS atomics by 23 us (R1:
    // atomicAdd(float*) lowers to a CAS loop, ~250cy serial chain per op).
    #pragma unroll
    for (int j = 0; j < NUM_INST; ++j) {
        bool m = (k == j);
        s12[j] += m ? e12 : 0.0f;                       // v_cmp + cndmask + add
        cnt_s[j] += (unsigned)__popcll(__ballot(m));    // s_bcnt1 + s_add (scalar pipe)
    }
}

__global__ __launch_bounds__(THREADS, 8) void overlap_main_kernel(
    const float* __restrict__ preds, const float* __restrict__ conf,
    const int* __restrict__ inst, const float* __restrict__ overlap,
    float* __restrict__ ws)
{
    const int b   = blockIdx.y;
    const int tid = threadIdx.x;

    const float4* p1v = (const float4*)(preds + (size_t)b * 2 * HWN);
    const float4* p2v = p1v + NVEC;
    const float4* cv  = (const float4*)(conf    + (size_t)b * HWN);
    const float4* tv  = (const float4*)(overlap + (size_t)b * HWN);
    const int4*   kv  = (const int4*)(inst      + (size_t)b * HWN);

    float s12[NUM_INST];
    unsigned cnt_s[NUM_INST];
    #pragma unroll
    for (int j = 0; j < NUM_INST; ++j) { s12[j] = 0.0f; cnt_s[j] = 0u; }
    float lgPos = 0.0f, lgAll = 0.0f, lgOr = 0.0f, accCnt = 0.0f;

    // Contiguous 400-vec4 chunk per block: every block does identical work,
    // no cross-CU tail imbalance (grid-stride gave blocks 0..15 +33% work).
    // Divergent partial last iteration is fine: __ballot only counts active lanes.
    const int lim = (blockIdx.x + 1) * VPB;
    for (int i = blockIdx.x * VPB + tid; i < lim; i += THREADS) {
        float4 A  = p1v[i];
        float4 Bv = p2v[i];
        float4 C  = cv[i];
        float4 T  = tv[i];
        int4   K  = kv[i];
        process_pixel(A.x, Bv.x, C.x, T.x, K.x, s12, cnt_s, lgPos, lgAll, lgOr, accCnt);
        process_pixel(A.y, Bv.y, C.y, T.y, K.y, s12, cnt_s, lgPos, lgAll, lgOr, accCnt);
        process_pixel(A.z, Bv.z, C.z, T.z, K.z, s12, cnt_s, lgPos, lgAll, lgOr, accCnt);
        process_pixel(A.w, Bv.w, C.w, T.w, K.w, s12, cnt_s, lgPos, lgAll, lgOr, accCnt);
    }

    // Butterfly-reduce the 20 per-lane floats (cnt bins are wave-uniform SGPRs)
    float fv[20];
    #pragma unroll
    for (int j = 0; j < NUM_INST; ++j) fv[j] = s12[j];
    fv[16] = lgPos; fv[17] = lgAll; fv[18] = lgOr; fv[19] = accCnt;
    #pragma unroll
    for (int s = 32; s > 0; s >>= 1) {
        #pragma unroll
        for (int v = 0; v < 20; ++v) fv[v] += __shfl_xor(fv[v], s, 64);
    }

    __shared__ float wsum[4][NV];
    const int wave = tid >> 6;
    const int lane = tid & 63;
    if (lane == 0) {
        #pragma unroll
        for (int j = 0; j < NUM_INST; ++j) {
            wsum[wave][j]      = fv[j];
            wsum[wave][16 + j] = (float)cnt_s[j];
        }
        wsum[wave][32] = fv[16];   // sum(c*log2)
        wsum[wave][33] = fv[17];   // sum(log2)
        wsum[wave][34] = fv[18];   // sum(log2) for or-term
        wsum[wave][35] = fv[19];   // posCnt
    }
    __syncthreads();
    if (tid < NV) {
        float s = wsum[0][tid] + wsum[1][tid] + wsum[2][tid] + wsum[3][tid];
        if (tid >= 32 && tid < 35)
            s = -0.69314718055994530942f * s;   // log2 -> -ln: posSum, allSum, orSum
        int g = blockIdx.y * NBLK + blockIdx.x;
        ws[tid * NBLK_TOT + g] = s;             // plain store, no atomics
    }
}

__global__ __launch_bounds__(640) void overlap_finalize_kernel(
    const float* __restrict__ ws, float* __restrict__ out)
{
    __shared__ float seg2[BB][NV][2];
    __shared__ float seg[BB][NV];
    __shared__ float perkey[BB][NUM_INST];
    __shared__ float pres[BB][NUM_INST];
    __shared__ float binst[BB];
    const int t = threadIdx.x;   // 640 >= 8*36*2 = 576

    if (t < BB * NV * 2) {
        int idx = t >> 1, half = t & 1;
        int b = idx / NV, v = idx - (idx / NV) * NV;
        const float4* p = (const float4*)(ws + v * NBLK_TOT + b * NBLK) + half * (NBLK / 8);
        float4 s4 = {0.0f, 0.0f, 0.0f, 0.0f};
        #pragma unroll 8
        for (int i = 0; i < NBLK / 8; ++i) {   // 32 independent float4 loads each
            float4 q = p[i];
            s4.x += q.x; s4.y += q.y; s4.z += q.z; s4.w += q.w;
        }
        seg2[b][v][half] = (s4.x + s4.y) + (s4.z + s4.w);
    }
    __syncthreads();

    if (t < BB * NV) {
        int b = t / NV, v = t - (t / NV) * NV;
        seg[b][v] = seg2[b][v][0] + seg2[b][v][1];
    }
    __syncthreads();

    if (t < BB * NUM_INST) {
        int b = t >> 4, k = t & 15;
        float c = seg[b][16 + k];
        bool present = c > 0.0f;
        float sc = present ? c : 1.0f;
        perkey[b][k] = present ? (1.0f - fabsf(seg[b][k]) / sc) : 0.0f;
        pres[b][k]   = present ? 1.0f : 0.0f;
    }
    __syncthreads();

    if (t < BB) {
        float s = 0.0f, nk = 0.0f;
        for (int k = 0; k < NUM_INST; ++k) { s += perkey[t][k]; nk += pres[t][k]; }
        binst[t] = s / nk;
    }
    __syncthreads();

    if (t == 0) {
        float instLoss = 0.0f, posS = 0.0f, allS = 0.0f, orS = 0.0f, posC = 0.0f;
        for (int b = 0; b < BB; ++b) {
            instLoss += binst[b];
            posS += seg[b][32];
            allS += seg[b][33];
            orS  += seg[b][34];
            posC += seg[b][35];
        }
        instLoss *= (1.0f / (float)BB);
        const float N = (float)BB * (float)HWN;
        float negS = allS - posS;
        float andLoss = posS / posC + negS / (N - posC);
        float orLoss  = orS / N;
        out[0] = 0.5f * andLoss + 0.25f * orLoss + 0.25f * instLoss;
    }
}

extern "C" void kernel_launch(void* const* d_in, const int* in_sizes, int n_in,
                              void* d_out, int out_size, void* d_ws, size_t ws_size,
                              hipStream_t stream) {
    const float* preds   = (const float*)d_in[0];
    const float* conf    = (const float*)d_in[1];
    const int*   inst    = (const int*)d_in[2];
    const float* overlap = (const float*)d_in[3];
    // d_in[4] (inds) is unused by the reference computation.
    float* ws  = (float*)d_ws;
    float* out = (float*)d_out;

    dim3 grid(NBLK, BB);
    overlap_main_kernel<<<grid, THREADS, 0, stream>>>(preds, conf, inst, overlap, ws);
    overlap_finalize_kernel<<<1, 640, 0, stream>>>(ws, out);
}

// Round 3
// 116.367 us; speedup vs baseline: 1.1853x; 1.0072x over previous
//
#include <hip/hip_runtime.h>

// Problem constants
#define BB 8
#define HH 640
#define WW 640
#define HWN (HH * WW)          // 409600 pixels per batch
#define NUM_INST 16
#define NBLK 64                // blocks per batch -> 512 total = 2 blocks/CU
#define NBLK_TOT (NBLK * BB)   // 512
#define THREADS 320            // 5 waves; 1600 vec4/block -> EXACTLY 5 vec4/thread
#define NWAVE (THREADS / 64)   // 5
#define NV 36                  // 16 s12 | 16 cnt | pos, all, or, posCnt
#define NVEC (HWN / 4)         // 102400 float4 per batch
#define VPB (NVEC / NBLK)      // 1600 float4 per block -> perfectly balanced
#define ITER (VPB / THREADS)   // 5 -> no loop, no tail, full unroll

// ws layout: ws[v * NBLK_TOT + g], g = b*NBLK + blockIdx.x. 36*512*4 = 73728 B.
// Plain stores, no zero-init needed.

__device__ __forceinline__ void process_pixel(
    float p1, float p2, float c, float t, int k,
    float* s12, unsigned* cnt_s,
    float& lgPos, float& lgAll, float& lgOr, float& accCnt)
{
    float andp = p1 * p2;
    bool tpos = (t != 0.0f);
    bool cpos = (c != 0.0f);
    // BCE(and_preds, overlap): overlap exactly 0/1 -> one log, select the argument.
    // Clip at -100 never engages: inputs in [1e-4, 1-1e-4].
    // Accumulate log2; scale by ln2 and negate ONCE in the epilogue.
    float argA = tpos ? andp : (1.0f - andp);
    float lg = __log2f(argA);          // raw v_log_f32
    lgAll += lg;
    lgPos = fmaf(c, lg, lgPos);        // c is exactly 0.0/1.0
    accCnt += c;
    // BCE(max(p1,p2), conf): conf exactly 0/1
    float mx = fmaxf(p1, p2);
    float argO = cpos ? mx : (1.0f - mx);
    lgOr += __log2f(argO);
    // instance term: |d1-d2| = |s1-s2|/cnt, accumulate e1-e2 only
    float ao = t * andp;               // t is exactly 0.0/1.0
    float d1 = fmaxf(p1, ao) - 1.0f;
    float d2 = fmaxf(p2, ao) - 1.0f;
    float e12 = (d1 - d2) * (d1 + d2);
    // Register binning ladder (~2 us chip-wide total; R1 showed LDS float
    // atomics lower to a CAS loop and cost +23 us). The v_cmp result feeds
    // both the cndmask (s12) and the ballot (counts on the scalar pipe).
    #pragma unroll
    for (int j = 0; j < NUM_INST; ++j) {
        bool m = (k == j);
        s12[j] += m ? e12 : 0.0f;                       // v_cmp + cndmask + add
        cnt_s[j] += (unsigned)__popcll(__ballot(m));    // s_bcnt1 + s_add (scalar pipe)
    }
}

__global__ __launch_bounds__(THREADS, 4) void overlap_main_kernel(
    const float* __restrict__ preds, const float* __restrict__ conf,
    const int* __restrict__ inst, const float* __restrict__ overlap,
    float* __restrict__ ws)
{
    const int b   = blockIdx.y;
    const int tid = threadIdx.x;
    const int bs  = blockIdx.x * VPB;   // contiguous 1600-vec4 chunk per block

    const float4* p1v = (const float4*)(preds + (size_t)b * 2 * HWN);
    const float4* p2v = p1v + NVEC;
    const float4* cv  = (const float4*)(conf    + (size_t)b * HWN);
    const float4* tv  = (const float4*)(overlap + (size_t)b * HWN);
    const int4*   kv  = (const int4*)(inst      + (size_t)b * HWN);

    // Issue ALL 25 independent loads up front: max memory-level parallelism,
    // no loop-carried vmcnt(0) serialization (R2 hit that via the 64-VGPR cap).
    float4 A[ITER], Bv[ITER], C[ITER], T[ITER];
    int4   K[ITER];
    #pragma unroll
    for (int it = 0; it < ITER; ++it) {
        int i = bs + it * THREADS + tid;   // static indices -> registers (rule #20)
        A[it]  = p1v[i];
        Bv[it] = p2v[i];
        C[it]  = cv[i];
        T[it]  = tv[i];
        K[it]  = kv[i];
    }

    float s12[NUM_INST];
    unsigned cnt_s[NUM_INST];
    #pragma unroll
    for (int j = 0; j < NUM_INST; ++j) { s12[j] = 0.0f; cnt_s[j] = 0u; }
    float lgPos = 0.0f, lgAll = 0.0f, lgOr = 0.0f, accCnt = 0.0f;

    #pragma unroll
    for (int it = 0; it < ITER; ++it) {
        process_pixel(A[it].x, Bv[it].x, C[it].x, T[it].x, K[it].x, s12, cnt_s, lgPos, lgAll, lgOr, accCnt);
        process_pixel(A[it].y, Bv[it].y, C[it].y, T[it].y, K[it].y, s12, cnt_s, lgPos, lgAll, lgOr, accCnt);
        process_pixel(A[it].z, Bv[it].z, C[it].z, T[it].z, K[it].z, s12, cnt_s, lgPos, lgAll, lgOr, accCnt);
        process_pixel(A[it].w, Bv[it].w, C[it].w, T[it].w, K[it].w, s12, cnt_s, lgPos, lgAll, lgOr, accCnt);
    }

    // Butterfly-reduce the 20 per-lane floats (cnt bins are wave-uniform SGPRs)
    float fv[20];
    #pragma unroll
    for (int j = 0; j < NUM_INST; ++j) fv[j] = s12[j];
    fv[16] = lgPos; fv[17] = lgAll; fv[18] = lgOr; fv[19] = accCnt;
    #pragma unroll
    for (int s = 32; s > 0; s >>= 1) {
        #pragma unroll
        for (int v = 0; v < 20; ++v) fv[v] += __shfl_xor(fv[v], s, 64);
    }

    __shared__ float wsum[NWAVE][NV];
    const int wave = tid >> 6;
    const int lane = tid & 63;
    if (lane == 0) {
        #pragma unroll
        for (int j = 0; j < NUM_INST; ++j) {
            wsum[wave][j]      = fv[j];
            wsum[wave][16 + j] = (float)cnt_s[j];
        }
        wsum[wave][32] = fv[16];   // sum(c*log2)
        wsum[wave][33] = fv[17];   // sum(log2) and-term
        wsum[wave][34] = fv[18];   // sum(log2) or-term
        wsum[wave][35] = fv[19];   // posCnt
    }
    __syncthreads();
    if (tid < NV) {
        float s = 0.0f;
        #pragma unroll
        for (int w = 0; w < NWAVE; ++w) s += wsum[w][tid];
        if (tid >= 32 && tid < 35)
            s = -0.69314718055994530942f * s;   // log2 -> -ln: posSum, allSum, orSum
        int g = blockIdx.y * NBLK + blockIdx.x;
        ws[tid * NBLK_TOT + g] = s;             // plain store, no atomics
    }
}

__global__ __launch_bounds__(320) void overlap_finalize_kernel(
    const float* __restrict__ ws, float* __restrict__ out)
{
    __shared__ float seg[BB][NV];
    __shared__ float perkey[BB][NUM_INST];
    __shared__ float pres[BB][NUM_INST];
    __shared__ float binst[BB];
    const int t = threadIdx.x;   // 320 >= 8*36 = 288

    if (t < BB * NV) {
        int b = t / NV, v = t - (t / NV) * NV;
        const float4* p = (const float4*)(ws + v * NBLK_TOT + b * NBLK);
        float4 s4 = {0.0f, 0.0f, 0.0f, 0.0f};
        #pragma unroll
        for (int i = 0; i < NBLK / 4; ++i) {   // 16 independent float4 loads
            float4 q = p[i];
            s4.x += q.x; s4.y += q.y; s4.z += q.z; s4.w += q.w;
        }
        seg[b][v] = (s4.x + s4.y) + (s4.z + s4.w);
    }
    __syncthreads();

    if (t < BB * NUM_INST) {
        int b = t >> 4, k = t & 15;
        float c = seg[b][16 + k];
        bool present = c > 0.0f;
        float sc = present ? c : 1.0f;
        perkey[b][k] = present ? (1.0f - fabsf(seg[b][k]) / sc) : 0.0f;
        pres[b][k]   = present ? 1.0f : 0.0f;
    }
    __syncthreads();

    if (t < BB) {
        float s = 0.0f, nk = 0.0f;
        for (int k = 0; k < NUM_INST; ++k) { s += perkey[t][k]; nk += pres[t][k]; }
        binst[t] = s / nk;
    }
    __syncthreads();

    if (t == 0) {
        float instLoss = 0.0f, posS = 0.0f, allS = 0.0f, orS = 0.0f, posC = 0.0f;
        for (int b = 0; b < BB; ++b) {
            instLoss += binst[b];
            posS += seg[b][32];
            allS += seg[b][33];
            orS  += seg[b][34];
            posC += seg[b][35];
        }
        instLoss *= (1.0f / (float)BB);
        const float N = (float)BB * (float)HWN;
        float negS = allS - posS;
        float andLoss = posS / posC + negS / (N - posC);
        float orLoss  = orS / N;
        out[0] = 0.5f * andLoss + 0.25f * orLoss + 0.25f * instLoss;
    }
}

extern "C" void kernel_launch(void* const* d_in, const int* in_sizes, int n_in,
                              void* d_out, int out_size, void* d_ws, size_t ws_size,
                              hipStream_t stream) {
    const float* preds   = (const float*)d_in[0];
    const float* conf    = (const float*)d_in[1];
    const int*   inst    = (const int*)d_in[2];
    const float* overlap = (const float*)d_in[3];
    // d_in[4] (inds) is unused by the reference computation.
    float* ws  = (float*)d_ws;
    float* out = (float*)d_out;

    dim3 grid(NBLK, BB);
    overlap_main_kernel<<<grid, THREADS, 0, stream>>>(preds, conf, inst, overlap, ws);
    overlap_finalize_kernel<<<1, 320, 0, stream>>>(ws, out);
}

// Round 4
// 108.412 us; speedup vs baseline: 1.2722x; 1.0734x over previous
//
#include <hip/hip_runtime.h>

// Problem constants
#define BB 8
#define HH 640
#define WW 640
#define HWN (HH * WW)          // 409600 pixels per batch
#define NUM_INST 16
#define NBLK 128               // blocks per batch -> 1024 total = 4 blocks/CU (R0-proven)
#define NBLK_TOT (NBLK * BB)   // 1024
#define THREADS 256
#define NV 36                  // 16 s12 | 16 cnt | pos, all, or, posCnt
#define NVEC (HWN / 4)         // 102400 float4 per batch
#define VPB (NVEC / NBLK)      // 800 float4 per block: 3 full rounds + 32-thread tail

// ws layout: ws[v * NBLK_TOT + g], g = b*NBLK + blockIdx.x. 36*1024*4 = 147456 B.
// Plain stores, no zero-init needed.

__device__ __forceinline__ void process_pixel(
    float p1, float p2, float c, float t, int k,
    float* s12, unsigned* cnt_s,
    float& lgPos, float& lgAll, float& lgOr, float& accCnt)
{
    float andp = p1 * p2;
    bool tpos = (t != 0.0f);
    bool cpos = (c != 0.0f);
    // BCE(and_preds, overlap): overlap exactly 0/1 -> one log, select the argument.
    // Clip at -100 never engages: inputs in [1e-4, 1-1e-4].
    // Accumulate log2; scale by ln2 and negate ONCE in the epilogue (absmax=0 in R2/R3).
    float argA = tpos ? andp : (1.0f - andp);
    float lg = __log2f(argA);          // raw v_log_f32
    lgAll += lg;
    lgPos = fmaf(c, lg, lgPos);        // c is exactly 0.0/1.0
    accCnt += c;
    // BCE(max(p1,p2), conf): conf exactly 0/1
    float mx = fmaxf(p1, p2);
    float argO = cpos ? mx : (1.0f - mx);
    lgOr += __log2f(argO);
    // instance term: |d1-d2| = |s1-s2|/cnt, accumulate e1-e2 only
    float ao = t * andp;               // t is exactly 0.0/1.0
    float d1 = fmaxf(p1, ao) - 1.0f;
    float d2 = fmaxf(p2, ao) - 1.0f;
    float e12 = (d1 - d2) * (d1 + d2);
    // Register binning ladder (~2.5 us chip-wide total). R1 proved LDS float
    // atomics lower to a CAS loop (+23 us). Counts ride the scalar pipe.
    #pragma unroll
    for (int j = 0; j < NUM_INST; ++j) {
        bool m = (k == j);
        s12[j] += m ? e12 : 0.0f;                       // v_cmp + cndmask + add
        cnt_s[j] += (unsigned)__popcll(__ballot(m));    // s_bcnt1 + s_add (scalar pipe)
    }
}

// (256,4): min 4 waves/EU -> VGPR cap 128 (no spill headroom needed beyond
// ~100 live regs for 3-round payload), guarantees the R0-proven 4 blocks/CU.
__global__ __launch_bounds__(THREADS, 4) void overlap_main_kernel(
    const float* __restrict__ preds, const float* __restrict__ conf,
    const int* __restrict__ inst, const float* __restrict__ overlap,
    float* __restrict__ ws)
{
    const int b   = blockIdx.y;
    const int tid = threadIdx.x;
    const int bs  = blockIdx.x * VPB;   // contiguous 800-vec4 chunk per block

    const float4* p1v = (const float4*)(preds + (size_t)b * 2 * HWN);
    const float4* p2v = p1v + NVEC;
    const float4* cv  = (const float4*)(conf    + (size_t)b * HWN);
    const float4* tv  = (const float4*)(overlap + (size_t)b * HWN);
    const int4*   kv  = (const int4*)(inst      + (size_t)b * HWN);

    float s12[NUM_INST];
    unsigned cnt_s[NUM_INST];
    #pragma unroll
    for (int j = 0; j < NUM_INST; ++j) { s12[j] = 0.0f; cnt_s[j] = 0u; }
    float lgPos = 0.0f, lgAll = 0.0f, lgOr = 0.0f, accCnt = 0.0f;

    // 3 full rounds (768 vec4) — R0-style load-then-compute per round; the
    // unroll lets the compiler hoist next-round loads as registers allow.
    #pragma unroll
    for (int it = 0; it < 3; ++it) {
        int i = bs + it * THREADS + tid;
        float4 A  = p1v[i];
        float4 Bv = p2v[i];
        float4 C  = cv[i];
        float4 T  = tv[i];
        int4   K  = kv[i];
        process_pixel(A.x, Bv.x, C.x, T.x, K.x, s12, cnt_s, lgPos, lgAll, lgOr, accCnt);
        process_pixel(A.y, Bv.y, C.y, T.y, K.y, s12, cnt_s, lgPos, lgAll, lgOr, accCnt);
        process_pixel(A.z, Bv.z, C.z, T.z, K.z, s12, cnt_s, lgPos, lgAll, lgOr, accCnt);
        process_pixel(A.w, Bv.w, C.w, T.w, K.w, s12, cnt_s, lgPos, lgAll, lgOr, accCnt);
    }
    // 32-vec4 remainder: half of wave 0 only (~1 extra round for 1/32 of the
    // block vs R0's whole-block +33% imbalance). __ballot counts active lanes.
    if (tid < VPB - 3 * THREADS) {
        int i = bs + 3 * THREADS + tid;
        float4 A  = p1v[i];
        float4 Bv = p2v[i];
        float4 C  = cv[i];
        float4 T  = tv[i];
        int4   K  = kv[i];
        process_pixel(A.x, Bv.x, C.x, T.x, K.x, s12, cnt_s, lgPos, lgAll, lgOr, accCnt);
        process_pixel(A.y, Bv.y, C.y, T.y, K.y, s12, cnt_s, lgPos, lgAll, lgOr, accCnt);
        process_pixel(A.z, Bv.z, C.z, T.z, K.z, s12, cnt_s, lgPos, lgAll, lgOr, accCnt);
        process_pixel(A.w, Bv.w, C.w, T.w, K.w, s12, cnt_s, lgPos, lgAll, lgOr, accCnt);
    }

    // Butterfly-reduce the 20 per-lane floats (cnt bins are wave-uniform SGPRs)
    float fv[20];
    #pragma unroll
    for (int j = 0; j < NUM_INST; ++j) fv[j] = s12[j];
    fv[16] = lgPos; fv[17] = lgAll; fv[18] = lgOr; fv[19] = accCnt;
    #pragma unroll
    for (int s = 32; s > 0; s >>= 1) {
        #pragma unroll
        for (int v = 0; v < 20; ++v) fv[v] += __shfl_xor(fv[v], s, 64);
    }

    __shared__ float wsum[4][NV];
    const int wave = tid >> 6;
    const int lane = tid & 63;
    if (lane == 0) {
        #pragma unroll
        for (int j = 0; j < NUM_INST; ++j) {
            wsum[wave][j]      = fv[j];
            wsum[wave][16 + j] = (float)cnt_s[j];
        }
        wsum[wave][32] = fv[16];   // sum(c*log2)
        wsum[wave][33] = fv[17];   // sum(log2) and-term
        wsum[wave][34] = fv[18];   // sum(log2) or-term
        wsum[wave][35] = fv[19];   // posCnt
    }
    __syncthreads();
    if (tid < NV) {
        float s = wsum[0][tid] + wsum[1][tid] + wsum[2][tid] + wsum[3][tid];
        if (tid >= 32 && tid < 35)
            s = -0.69314718055994530942f * s;   // log2 -> -ln: posSum, allSum, orSum
        int g = blockIdx.y * NBLK + blockIdx.x;
        ws[tid * NBLK_TOT + g] = s;             // plain store, no atomics
    }
}

__global__ __launch_bounds__(320) void overlap_finalize_kernel(
    const float* __restrict__ ws, float* __restrict__ out)
{
    __shared__ float seg[BB][NV];
    __shared__ float perkey[BB][NUM_INST];
    __shared__ float pres[BB][NUM_INST];
    __shared__ float binst[BB];
    const int t = threadIdx.x;   // 320 >= 8*36 = 288

    if (t < BB * NV) {
        int b = t / NV, v = t - (t / NV) * NV;
        const float4* p = (const float4*)(ws + v * NBLK_TOT + b * NBLK);
        float4 s4 = {0.0f, 0.0f, 0.0f, 0.0f};
        #pragma unroll 8
        for (int i = 0; i < NBLK / 4; ++i) {   // 32 independent float4 loads
            float4 q = p[i];
            s4.x += q.x; s4.y += q.y; s4.z += q.z; s4.w += q.w;
        }
        seg[b][v] = (s4.x + s4.y) + (s4.z + s4.w);
    }
    __syncthreads();

    if (t < BB * NUM_INST) {
        int b = t >> 4, k = t & 15;
        float c = seg[b][16 + k];
        bool present = c > 0.0f;
        float sc = present ? c : 1.0f;
        perkey[b][k] = present ? (1.0f - fabsf(seg[b][k]) / sc) : 0.0f;
        pres[b][k]   = present ? 1.0f : 0.0f;
    }
    __syncthreads();

    if (t < BB) {
        float s = 0.0f, nk = 0.0f;
        for (int k = 0; k < NUM_INST; ++k) { s += perkey[t][k]; nk += pres[t][k]; }
        binst[t] = s / nk;
    }
    __syncthreads();

    if (t == 0) {
        float instLoss = 0.0f, posS = 0.0f, allS = 0.0f, orS = 0.0f, posC = 0.0f;
        for (int b = 0; b < BB; ++b) {
            instLoss += binst[b];
            posS += seg[b][32];
            allS += seg[b][33];
            orS  += seg[b][34];
            posC += seg[b][35];
        }
        instLoss *= (1.0f / (float)BB);
        const float N = (float)BB * (float)HWN;
        float negS = allS - posS;
        float andLoss = posS / posC + negS / (N - posC);
        float orLoss  = orS / N;
        out[0] = 0.5f * andLoss + 0.25f * orLoss + 0.25f * instLoss;
    }
}

extern "C" void kernel_launch(void* const* d_in, const int* in_sizes, int n_in,
                              void* d_out, int out_size, void* d_ws, size_t ws_size,
                              hipStream_t stream) {
    const float* preds   = (const float*)d_in[0];
    const float* conf    = (const float*)d_in[1];
    const int*   inst    = (const int*)d_in[2];
    const float* overlap = (const float*)d_in[3];
    // d_in[4] (inds) is unused by the reference computation.
    float* ws  = (float*)d_ws;
    float* out = (float*)d_out;

    dim3 grid(NBLK, BB);
    overlap_main_kernel<<<grid, THREADS, 0, stream>>>(preds, conf, inst, overlap, ws);
    overlap_finalize_kernel<<<1, 320, 0, stream>>>(ws, out);
}